// Round 13
// baseline (1003.380 us; speedup 1.0000x reference)
//
#include <hip/hip_runtime.h>

#define NFEAT 512
#define NCLS  40
#define NPAD  48          // NCLS padded to 3 MFMA n-tiles of 16
#define DM 128            // padded bucket width (legacy direct path)

// partition path parameters
#define NCB     256       // nodes per coarse bucket (c >> 8)
#define P1B     512       // phase-1 block count
#define CH      2048      // edges per LDS sort chunk
#define SCAP    64        // slice capacity per (bucket, block); mean 16
#define OVF_CAP 65536     // overflow ring capacity (virtually never used)

// aggregate kernel parameters
#define ELCAP   4096      // LDS edge list capacity per fill round
#define GRP     128       // slices consumed per fill round (mean 2048 edges)

typedef __attribute__((ext_vector_type(8))) short bf16x8;   // 8 bf16 (4 VGPRs)
typedef __attribute__((ext_vector_type(4))) float f32x4;

__device__ __forceinline__ unsigned short f2bf(float f) {   // RNE f32->bf16
    unsigned int u = __builtin_bit_cast(unsigned int, f);
    return (unsigned short)((u + 0x7FFFu + ((u >> 16) & 1u)) >> 16);
}
__device__ __forceinline__ float bf2f(unsigned short h) {
    return __builtin_bit_cast(float, (unsigned int)h << 16);
}

__device__ __forceinline__ void load_edge(const void* adj, int int32_mode,
                                          int e, int E, int& r, int& c) {
    if (int32_mode) {
        const int* a = (const int*)adj;
        r = a[e]; c = a[(size_t)E + e];
    } else {
        const long long* a = (const long long*)adj;
        r = (int)a[e]; c = (int)a[(size_t)E + e];
    }
}

// ---------------------------------------------------------------------------
// W [40][512] f32 -> Wb [48][512] bf16 (rows 40..47 zero) + zero scalars.
// ---------------------------------------------------------------------------
__global__ void wconv_kernel(const float* __restrict__ W,
                             unsigned short* __restrict__ Wb,
                             unsigned int* __restrict__ flag,
                             int* __restrict__ ovf_cnt) {
    int i = blockIdx.x * blockDim.x + threadIdx.x;
    if (i == 0) { *flag = 0u; *ovf_cnt = 0; }
    if (i >= NPAD * NFEAT) return;
    int n = i >> 9;
    float v = (n < NCLS) ? W[i] : 0.0f;
    Wb[i] = f2bf(v);
}

// ---------------------------------------------------------------------------
// GEMM: f32 x loads, in-register bf16 convert, MFMA, bf16 output.
// ---------------------------------------------------------------------------
__global__ __launch_bounds__(256) void gemm_kernel(
        const float* __restrict__ x, const unsigned short* __restrict__ Wb,
        unsigned short* __restrict__ xwb, int N) {
    const int wid  = (blockIdx.x * blockDim.x + threadIdx.x) >> 6;
    const int lane = threadIdx.x & 63;
    const int m0 = wid * 16;
    if (m0 >= N) return;
    const int frow = lane & 15, ks = lane >> 4;
    int grow = m0 + frow; if (grow > N - 1) grow = N - 1;
    const float* xr = x + (size_t)grow * NFEAT + ks * 8;
    const unsigned short* wb0 = Wb + (size_t)frow * NFEAT + ks * 8;
    const unsigned short* wb1 = wb0 + (size_t)16 * NFEAT;
    const unsigned short* wb2 = wb0 + (size_t)32 * NFEAT;

    f32x4 acc0 = {0.f, 0.f, 0.f, 0.f};
    f32x4 acc1 = {0.f, 0.f, 0.f, 0.f};
    f32x4 acc2 = {0.f, 0.f, 0.f, 0.f};

#pragma unroll
    for (int kk = 0; kk < NFEAT; kk += 32) {
        float4 xa = *reinterpret_cast<const float4*>(xr + kk);
        float4 xb = *reinterpret_cast<const float4*>(xr + kk + 4);
        bf16x8 a;
        a[0] = (short)f2bf(xa.x); a[1] = (short)f2bf(xa.y);
        a[2] = (short)f2bf(xa.z); a[3] = (short)f2bf(xa.w);
        a[4] = (short)f2bf(xb.x); a[5] = (short)f2bf(xb.y);
        a[6] = (short)f2bf(xb.z); a[7] = (short)f2bf(xb.w);
        bf16x8 b0 = *reinterpret_cast<const bf16x8*>(wb0 + kk);
        bf16x8 b1 = *reinterpret_cast<const bf16x8*>(wb1 + kk);
        bf16x8 b2 = *reinterpret_cast<const bf16x8*>(wb2 + kk);
        acc0 = __builtin_amdgcn_mfma_f32_16x16x32_bf16(a, b0, acc0, 0, 0, 0);
        acc1 = __builtin_amdgcn_mfma_f32_16x16x32_bf16(a, b1, acc1, 0, 0, 0);
        acc2 = __builtin_amdgcn_mfma_f32_16x16x32_bf16(a, b2, acc2, 0, 0, 0);
    }

    const int ccol = frow;
#pragma unroll
    for (int i = 0; i < 4; ++i) {
        int crow = m0 + ks * 4 + i;
        if (crow < N) {
            unsigned short* orow = xwb + (size_t)crow * NCLS;
            orow[ccol]      = f2bf(acc0[i]);
            orow[16 + ccol] = f2bf(acc1[i]);
            if (ccol < 8) orow[32 + ccol] = f2bf(acc2[i]);
        }
    }
}

// ---------------------------------------------------------------------------
// Phase 1 (unchanged from R11): LDS chunk-sort into per-(bucket,block) slices.
// ---------------------------------------------------------------------------
__global__ __launch_bounds__(256) void phase1_kernel(
        const void* __restrict__ adj,
        unsigned int* __restrict__ slices,
        int* __restrict__ slice_cnt,
        unsigned long long* __restrict__ ovf,
        int* __restrict__ ovf_cnt,
        int E, int N, int NB) {
    __shared__ unsigned int   pbuf[CH];     // packed (c&255)<<17 | r
    __shared__ unsigned short bbuf[CH];     // bucket id (0xFFFF invalid)
    __shared__ unsigned int   sbuf[CH];     // sorted packed
    __shared__ unsigned int   obuf[CH];     // sorted global target
    __shared__ int hist[512], base[512], cur[512], gcur[512];
    __shared__ int scn[256];
    __shared__ unsigned int det;

    const int t = threadIdx.x, blk = blockIdx.x;
    for (int i = t; i < 512; i += 256) gcur[i] = 0;
    if (t == 0) det = 0u;
    __syncthreads();
    const unsigned int* aw = (const unsigned int*)adj;
    unsigned int dv = aw[2 * t + 1] | aw[2 * (t + 256) + 1];
    if (dv) atomicOr(&det, 1u);
    __syncthreads();
    const int m32 = (det != 0);

    const int per_blk = (E + P1B - 1) / P1B;
    const int e0 = blk * per_blk;
    const int e1 = min(E, e0 + per_blk);

    for (int cb = e0; cb < e1; cb += CH) {
        const int n = min(CH, e1 - cb);
        for (int i = t; i < CH; i += 256) {
            unsigned short b = 0xFFFFu; unsigned int p = 0;
            if (i < n) {
                int r, c;
                load_edge(adj, m32, cb + i, E, r, c);
                if (r != c && (unsigned)r < (unsigned)N && (unsigned)c < (unsigned)N) {
                    b = (unsigned short)(c >> 8);
                    p = ((unsigned int)(c & 255) << 17) | (unsigned int)r;
                }
            }
            bbuf[i] = b; pbuf[i] = p;
        }
        for (int i = t; i < 512; i += 256) hist[i] = 0;
        __syncthreads();
        for (int i = t; i < CH; i += 256) {
            unsigned short b = bbuf[i];
            if (b != 0xFFFFu) atomicAdd(&hist[b], 1);
        }
        __syncthreads();
        int h0 = hist[2 * t], h1 = hist[2 * t + 1];
        int s = h0 + h1;
        scn[t] = s;
        __syncthreads();
        for (int o = 1; o < 256; o <<= 1) {
            int v = (t >= o) ? scn[t - o] : 0;
            __syncthreads();
            scn[t] += v;
            __syncthreads();
        }
        int excl = scn[t] - s;
        base[2 * t] = excl;           cur[2 * t] = excl;
        base[2 * t + 1] = excl + h0;  cur[2 * t + 1] = excl + h0;
        __syncthreads();
        for (int i = t; i < CH; i += 256) {
            unsigned short b = bbuf[i];
            if (b != 0xFFFFu) {
                unsigned int p = pbuf[i];
                int pos = atomicAdd(&cur[b], 1);
                int rank = gcur[b] + (pos - base[b]);
                unsigned int tgt;
                if (rank < SCAP) {
                    tgt = ((unsigned int)b * P1B + (unsigned int)blk) * SCAP + rank;
                } else {
                    tgt = 0xFFFFFFFFu;
                    int oi = atomicAdd(ovf_cnt, 1);
                    if (oi < OVF_CAP)
                        ovf[oi] = ((unsigned long long)b << 32) | p;
                }
                sbuf[pos] = p;
                obuf[pos] = tgt;
            }
        }
        __syncthreads();
        const int nvalid = cur[511];
        for (int i = t; i < nvalid; i += 256) {
            unsigned int tgt = obuf[i];
            if (tgt != 0xFFFFFFFFu) slices[tgt] = sbuf[i];
        }
        gcur[2 * t]     += h0;
        gcur[2 * t + 1] += h1;
        __syncthreads();
    }

    for (int i = t; i < NB; i += 256)
        slice_cnt[(size_t)i * P1B + blk] = min(gcur[i], SCAP);
}

// ---------------------------------------------------------------------------
// Aggregate (replaces phase2 + gather): one block per bucket.
// LDS f32 accumulator [256 nodes][40 classes]; fill/consume rounds over the
// bucket's 512 slices; epilogue = scale*(acc+self)+bias, fully coalesced.
// ---------------------------------------------------------------------------
__global__ __launch_bounds__(256) void aggregate_kernel(
        const unsigned int* __restrict__ slices,
        const int* __restrict__ slice_cnt,
        const unsigned long long* __restrict__ ovf,
        const int* __restrict__ ovf_cnt,
        const unsigned short* __restrict__ xwb,
        const float* __restrict__ bias,
        float* __restrict__ out, int N) {
    __shared__ float acc[NCB * NCLS];       // 40 KB
    __shared__ int dcnt[NCB];               // 1 KB
    __shared__ unsigned int elist[ELCAP];   // 16 KB
    __shared__ int scnt[P1B];               // 2 KB
    __shared__ int ecnt;

    const int b = blockIdx.x, t = threadIdx.x;
    for (int i = t; i < NCB * NCLS; i += 256) acc[i] = 0.0f;
    dcnt[t] = 0;                            // blockDim == NCB == 256
    for (int i = t; i < P1B; i += 256) scnt[i] = slice_cnt[(size_t)b * P1B + i];
    if (t == 0) ecnt = 0;
    __syncthreads();

    const size_t sbase = (size_t)b * P1B * SCAP;
    const int lane = t & 63, w = t >> 6;
    const int g = lane / 10, cl = lane % 10;   // 6 edge groups x 10 class-quads
    const bool lact = (g < 6);

    for (int g0 = 0; g0 < P1B; g0 += GRP) {
        // fill: coalesced predicated scan of GRP slices' slots
        for (int i = t; i < GRP * SCAP; i += 256) {
            int s = g0 + (i >> 6), k = i & 63;        // SCAP == 64
            if (k < scnt[s]) {
                int pos = atomicAdd(&ecnt, 1);
                if (pos < ELCAP)
                    elist[pos] = slices[sbase + ((size_t)s << 6) + k];
            }
        }
        __syncthreads();
        const int m = min(ecnt, ELCAP);
        // consume: 24 edges per block-iteration (6 per wave)
        for (int e0 = w * 6; e0 < m; e0 += 24) {
            int e = e0 + g;
            if (lact && e < m) {
                unsigned int p = elist[e];
                int nl = p >> 17;                      // node-local (c & 255)
                int r  = p & 0x1FFFF;
                ushort4 v = *reinterpret_cast<const ushort4*>(
                    xwb + (size_t)r * NCLS + cl * 4);
                float* ap = &acc[nl * NCLS + cl * 4];
                atomicAdd(ap + 0, bf2f(v.x));
                atomicAdd(ap + 1, bf2f(v.y));
                atomicAdd(ap + 2, bf2f(v.z));
                atomicAdd(ap + 3, bf2f(v.w));
                if (cl == 0) atomicAdd(&dcnt[nl], 1);
            }
        }
        __syncthreads();
        if (t == 0) ecnt = 0;
        __syncthreads();
    }

    // overflow ring (essentially never populated)
    const int no = min(*ovf_cnt, OVF_CAP);
    for (int i = t; i < no; i += 256) {
        if ((int)(ovf[i] >> 32) == b) {
            unsigned int p = (unsigned int)ovf[i];
            int nl = p >> 17, r = p & 0x1FFFF;
            for (int j = 0; j < NCLS; ++j)
                atomicAdd(&acc[nl * NCLS + j], bf2f(xwb[(size_t)r * NCLS + j]));
            atomicAdd(&dcnt[nl], 1);
        }
    }
    __syncthreads();

    // epilogue: out = scale*(acc + self) + bias, coalesced flat writes
    const int c0 = b * NCB;
    const int rows = min(NCB, N - c0);
    if (rows <= 0) return;
    const int lim = rows * NCLS;
    const size_t obase = (size_t)c0 * NCLS;
    for (int i = t; i < lim; i += 256) {
        int n = i / NCLS;
        int j = i - n * NCLS;
        float scale = 1.0f / (float)(dcnt[n] + 1);
        float self = bf2f(xwb[obase + i]);
        out[obase + i] = fmaf(scale, acc[i] + self, bias[j]);
    }
}

// ===========================================================================
// LEGACY DIRECT PATH (fallback only)
// ===========================================================================
__global__ void detect_kernel(const unsigned int* __restrict__ w,
                              unsigned int* __restrict__ flag) {
    unsigned int v = 0;
    for (int i = 1 + 2 * (int)threadIdx.x; i < 65536; i += 2 * (int)blockDim.x)
        v |= w[i];
    if (v) atomicOr(flag, 1u);
}

__global__ void fused_bucket_kernel(const void* __restrict__ adj,
                                    const unsigned int* __restrict__ flag,
                                    int* __restrict__ cnt,
                                    int* __restrict__ src2, int E, int N) {
    int e = blockIdx.x * blockDim.x + threadIdx.x;
    if (e >= E) return;
    int r, c;
    load_edge(adj, *flag, e, E, r, c);
    if (r == c) return;
    if ((unsigned)r >= (unsigned)N || (unsigned)c >= (unsigned)N) return;
    int pos = atomicAdd(&cnt[c], 1);
    if (pos < DM) src2[(size_t)c * DM + pos] = r;
}

__global__ void gather_kernel(const unsigned short* __restrict__ xwb,
                              const int* __restrict__ deg,
                              const int* __restrict__ src,
                              const float* __restrict__ bias,
                              float* __restrict__ out, int N, int dm) {
    int wid = (blockIdx.x * blockDim.x + threadIdx.x) >> 6;
    int lane = threadIdx.x & 63;
    if (wid >= N) return;
    int start = wid * dm;
    int d = __builtin_amdgcn_readfirstlane(min(deg[wid], dm));

    const int g  = lane / 10;
    const int cl = lane % 10;
    const bool lact = (g < 6);
    float a0 = 0.f, a1 = 0.f, a2 = 0.f, a3 = 0.f;

    if (g == 0) {
        ushort4 v = *reinterpret_cast<const ushort4*>(
            xwb + (size_t)wid * NCLS + cl * 4);
        a0 = bf2f(v.x); a1 = bf2f(v.y); a2 = bf2f(v.z); a3 = bf2f(v.w);
    }

    const int* sp = src + start;
    for (int e = 0; e < d; e += 12) {
        int i0 = e + g, i1 = e + 6 + g;
        if (lact && i0 < d) {
            int r = sp[i0];
            ushort4 v = *reinterpret_cast<const ushort4*>(
                xwb + (size_t)r * NCLS + cl * 4);
            a0 += bf2f(v.x); a1 += bf2f(v.y); a2 += bf2f(v.z); a3 += bf2f(v.w);
        }
        if (lact && i1 < d) {
            int r = sp[i1];
            ushort4 v = *reinterpret_cast<const ushort4*>(
                xwb + (size_t)r * NCLS + cl * 4);
            a0 += bf2f(v.x); a1 += bf2f(v.y); a2 += bf2f(v.z); a3 += bf2f(v.w);
        }
    }

    a0 += __shfl_down(a0, 30); a1 += __shfl_down(a1, 30);
    a2 += __shfl_down(a2, 30); a3 += __shfl_down(a3, 30);
    {
        float u0 = __shfl_down(a0, 10), v0 = __shfl_down(a0, 20);
        float u1 = __shfl_down(a1, 10), v1 = __shfl_down(a1, 20);
        float u2 = __shfl_down(a2, 10), v2 = __shfl_down(a2, 20);
        float u3 = __shfl_down(a3, 10), v3 = __shfl_down(a3, 20);
        a0 += u0 + v0; a1 += u1 + v1; a2 += u2 + v2; a3 += u3 + v3;
    }

    if (lane < 10) {
        float scale = 1.0f / (float)(d + 1);
        float4 bb = *reinterpret_cast<const float4*>(bias + cl * 4);
        float4 o;
        o.x = fmaf(scale, a0, bb.x);
        o.y = fmaf(scale, a1, bb.y);
        o.z = fmaf(scale, a2, bb.z);
        o.w = fmaf(scale, a3, bb.w);
        *reinterpret_cast<float4*>(out + (size_t)wid * NCLS + cl * 4) = o;
    }
}

extern "C" void kernel_launch(void* const* d_in, const int* in_sizes, int n_in,
                              void* d_out, int out_size, void* d_ws, size_t ws_size,
                              hipStream_t stream) {
    const float* x   = (const float*)d_in[0];
    const void*  adj = d_in[1];
    const float* W   = (const float*)d_in[2];
    const float* b   = (const float*)d_in[3];
    float* out = (float*)d_out;

    const int N = in_sizes[0] / NFEAT;   // 100000
    const int E = in_sizes[1] / 2;       // 3200000
    const int NB = (N + NCB - 1) / NCB;  // 391 coarse buckets
    const int GEMMB = (N + 63) / 64;

    char* ws = (char*)d_ws;
    size_t off = 0;
    auto alloc = [&](size_t bytes) { char* p = ws + off; off += (bytes + 15) & ~size_t(15); return p; };

    unsigned short* xwb = (unsigned short*)alloc((size_t)N * NCLS * 2);   // 8 MB
    int*   cnt          = (int*)  alloc((size_t)N * sizeof(int));
    unsigned int* flag  = (unsigned int*)alloc(16);
    int*   ovf_cnt      = (int*)  alloc(16);
    unsigned short* Wb  = (unsigned short*)alloc((size_t)NPAD * NFEAT * 2);

    const size_t part_need = off
        + (((size_t)NB * P1B * SCAP * 4 + 15) & ~size_t(15))        // slices 51 MB
        + (((size_t)NB * P1B * 4 + 15) & ~size_t(15))               // slice_cnt
        + (size_t)OVF_CAP * 8;                                      // ovf ring
    const bool partition = (N <= NCB * 512) && (NB <= 512) && (E >= 512)
                           && (part_need <= ws_size);
    const size_t direct_need = off + (size_t)N * DM * sizeof(int);
    const bool direct = !partition && (direct_need <= ws_size);

    wconv_kernel<<<(NPAD * NFEAT + 255) / 256, 256, 0, stream>>>(W, Wb, flag, ovf_cnt);

    if (partition) {
        unsigned int* slices = (unsigned int*)alloc((size_t)NB * P1B * SCAP * 4);
        int* slice_cnt = (int*)alloc((size_t)NB * P1B * 4);
        unsigned long long* ovf = (unsigned long long*)alloc((size_t)OVF_CAP * 8);

        phase1_kernel<<<P1B, 256, 0, stream>>>(adj, slices, slice_cnt,
                                               ovf, ovf_cnt, E, N, NB);
        gemm_kernel<<<GEMMB, 256, 0, stream>>>(x, Wb, xwb, N);
        aggregate_kernel<<<NB, 256, 0, stream>>>(slices, slice_cnt, ovf, ovf_cnt,
                                                 xwb, b, out, N);
    } else if (direct) {
        int* src2 = (int*)alloc((size_t)N * DM * sizeof(int));
        hipMemsetAsync(cnt, 0, (size_t)N * sizeof(int), stream);
        detect_kernel<<<1, 512, 0, stream>>>((const unsigned int*)adj, flag);
        gemm_kernel<<<GEMMB, 256, 0, stream>>>(x, Wb, xwb, N);
        fused_bucket_kernel<<<(E + 255) / 256, 256, 0, stream>>>(adj, flag, cnt, src2, E, N);
        gather_kernel<<<(N * 64 + 255) / 256, 256, 0, stream>>>(
            xwb, cnt, src2, b, out, N, DM);
    }
}

// Round 14
// 305.988 us; speedup vs baseline: 3.2792x; 3.2792x over previous
//
#include <hip/hip_runtime.h>

#define NFEAT 512
#define NCLS  40
#define NPAD  48          // NCLS padded to 3 MFMA n-tiles of 16
#define DM 128            // padded bucket width (legacy direct path)

// partition parameters
#define SBSH    10        // log2 nodes per super-bucket
#define SB      (1 << SBSH)          // 1024 nodes
#define NSBMAX  128
#define CH      4096      // edges per LDS sort chunk
#define P1B     512       // phase-1 block count
#define SBCAP   36864     // entries per super-bucket region (mean 32768)
#define BCAP3   16384     // CSR region per 256-node chunk (mean 8192)
#define OVF_CAP 65536     // overflow ring (virtually never used)

typedef __attribute__((ext_vector_type(8))) short bf16x8;   // 8 bf16 (4 VGPRs)
typedef __attribute__((ext_vector_type(4))) float f32x4;

__device__ __forceinline__ unsigned short f2bf(float f) {   // RNE f32->bf16
    unsigned int u = __builtin_bit_cast(unsigned int, f);
    return (unsigned short)((u + 0x7FFFu + ((u >> 16) & 1u)) >> 16);
}
__device__ __forceinline__ float bf2f(unsigned short h) {
    return __builtin_bit_cast(float, (unsigned int)h << 16);
}

__device__ __forceinline__ void load_edge(const void* adj, int int32_mode,
                                          int e, int E, int& r, int& c) {
    if (int32_mode) {
        const int* a = (const int*)adj;
        r = a[e]; c = a[(size_t)E + e];
    } else {
        const long long* a = (const long long*)adj;
        r = (int)a[e]; c = (int)a[(size_t)E + e];
    }
}

// ---------------------------------------------------------------------------
// W [40][512] f32 -> Wb [48][512] bf16 (rows 40..47 zero); zero control vars.
// ---------------------------------------------------------------------------
__global__ void wconv_kernel(const float* __restrict__ W,
                             unsigned short* __restrict__ Wb,
                             unsigned int* __restrict__ flag,
                             int* __restrict__ ovf_cnt,
                             int* __restrict__ gtot) {
    int i = blockIdx.x * blockDim.x + threadIdx.x;
    if (i == 0) { *flag = 0u; *ovf_cnt = 0; }
    if (blockIdx.x == 0 && threadIdx.x < NSBMAX) gtot[threadIdx.x] = 0;
    if (i >= NPAD * NFEAT) return;
    int n = i >> 9;
    float v = (n < NCLS) ? W[i] : 0.0f;
    Wb[i] = f2bf(v);
}

// ---------------------------------------------------------------------------
// GEMM: f32 x loads, in-register bf16 convert, MFMA, bf16 output. (verified)
// ---------------------------------------------------------------------------
__global__ __launch_bounds__(256) void gemm_kernel(
        const float* __restrict__ x, const unsigned short* __restrict__ Wb,
        unsigned short* __restrict__ xwb, int N) {
    const int wid  = (blockIdx.x * blockDim.x + threadIdx.x) >> 6;
    const int lane = threadIdx.x & 63;
    const int m0 = wid * 16;
    if (m0 >= N) return;
    const int frow = lane & 15, ks = lane >> 4;
    int grow = m0 + frow; if (grow > N - 1) grow = N - 1;
    const float* xr = x + (size_t)grow * NFEAT + ks * 8;
    const unsigned short* wb0 = Wb + (size_t)frow * NFEAT + ks * 8;
    const unsigned short* wb1 = wb0 + (size_t)16 * NFEAT;
    const unsigned short* wb2 = wb0 + (size_t)32 * NFEAT;

    f32x4 acc0 = {0.f, 0.f, 0.f, 0.f};
    f32x4 acc1 = {0.f, 0.f, 0.f, 0.f};
    f32x4 acc2 = {0.f, 0.f, 0.f, 0.f};

#pragma unroll
    for (int kk = 0; kk < NFEAT; kk += 32) {
        float4 xa = *reinterpret_cast<const float4*>(xr + kk);
        float4 xb = *reinterpret_cast<const float4*>(xr + kk + 4);
        bf16x8 a;
        a[0] = (short)f2bf(xa.x); a[1] = (short)f2bf(xa.y);
        a[2] = (short)f2bf(xa.z); a[3] = (short)f2bf(xa.w);
        a[4] = (short)f2bf(xb.x); a[5] = (short)f2bf(xb.y);
        a[6] = (short)f2bf(xb.z); a[7] = (short)f2bf(xb.w);
        bf16x8 b0 = *reinterpret_cast<const bf16x8*>(wb0 + kk);
        bf16x8 b1 = *reinterpret_cast<const bf16x8*>(wb1 + kk);
        bf16x8 b2 = *reinterpret_cast<const bf16x8*>(wb2 + kk);
        acc0 = __builtin_amdgcn_mfma_f32_16x16x32_bf16(a, b0, acc0, 0, 0, 0);
        acc1 = __builtin_amdgcn_mfma_f32_16x16x32_bf16(a, b1, acc1, 0, 0, 0);
        acc2 = __builtin_amdgcn_mfma_f32_16x16x32_bf16(a, b2, acc2, 0, 0, 0);
    }

    const int ccol = frow;
#pragma unroll
    for (int i = 0; i < 4; ++i) {
        int crow = m0 + ks * 4 + i;
        if (crow < N) {
            unsigned short* orow = xwb + (size_t)crow * NCLS;
            orow[ccol]      = f2bf(acc0[i]);
            orow[16 + ccol] = f2bf(acc1[i]);
            if (ccol < 8) orow[32 + ccol] = f2bf(acc2[i]);
        }
    }
}

// ---------------------------------------------------------------------------
// Phase 1: LDS chunk-sort into 98 SUPER-buckets (1024 nodes each) + global
// segment reservation. Segments avg ~42 edges -> ~1 line per 11 edges.
// p = (c & 1023) << 17 | r  (10 + 17 bits)
// ---------------------------------------------------------------------------
__global__ __launch_bounds__(256) void phase1_kernel(
        const void* __restrict__ adj,
        unsigned int* __restrict__ dst,      // [NSB][SBCAP]
        int* __restrict__ gtot,              // [NSBMAX] zeroed by wconv
        unsigned long long* __restrict__ ovf,
        int* __restrict__ ovf_cnt,
        int E, int N) {
    __shared__ unsigned int  pbuf[CH];       // 16 KB
    __shared__ unsigned char bbuf[CH];       // 4 KB
    __shared__ unsigned int  sbuf[CH];       // 16 KB
    __shared__ unsigned char bsort[CH];      // 4 KB
    __shared__ int hist[NSBMAX], base[NSBMAX], cur[NSBMAX], gofs[NSBMAX];
    __shared__ int scn[NSBMAX];
    __shared__ unsigned int det;

    const int t = threadIdx.x;
    if (t == 0) det = 0u;
    __syncthreads();
    // inline dtype detect: odd 32-bit words all-zero <=> int64 storage
    const unsigned int* aw = (const unsigned int*)adj;
    unsigned int dv = aw[2 * t + 1] | aw[2 * (t + 256) + 1];
    if (dv) atomicOr(&det, 1u);
    __syncthreads();
    const int m32 = (det != 0);

    const int nchunks = (E + CH - 1) / CH;
    for (int ci = blockIdx.x; ci < nchunks; ci += gridDim.x) {
        const int cb = ci * CH;
        const int n = min(CH, E - cb);
        // 1. load + classify (coalesced)
        for (int i = t; i < CH; i += 256) {
            unsigned char b = 0xFFu; unsigned int p = 0;
            if (i < n) {
                int r, c;
                load_edge(adj, m32, cb + i, E, r, c);
                if (r != c && (unsigned)r < (unsigned)N && (unsigned)c < (unsigned)N) {
                    b = (unsigned char)(c >> SBSH);
                    p = ((unsigned int)(c & (SB - 1)) << 17) | (unsigned int)r;
                }
            }
            bbuf[i] = b; pbuf[i] = p;
        }
        if (t < NSBMAX) hist[t] = 0;
        __syncthreads();
        // 2. histogram
        for (int i = t; i < CH; i += 256) {
            unsigned char b = bbuf[i];
            if (b != 0xFFu) atomicAdd(&hist[b], 1);
        }
        __syncthreads();
        // 3. exclusive scan over NSBMAX (threads t<128 active)
        int h = 0;
        if (t < NSBMAX) { h = hist[t]; scn[t] = h; }
        __syncthreads();
        for (int o = 1; o < NSBMAX; o <<= 1) {
            int v = (t < NSBMAX && t >= o) ? scn[t - o] : 0;
            __syncthreads();
            if (t < NSBMAX) scn[t] += v;
            __syncthreads();
        }
        if (t < NSBMAX) {
            int excl = scn[t] - h;
            base[t] = excl; cur[t] = excl;
            gofs[t] = (h > 0) ? atomicAdd(&gtot[t], h) : 0;  // reserve range
        }
        __syncthreads();
        // 4. scatter into sorted LDS order
        for (int i = t; i < CH; i += 256) {
            unsigned char b = bbuf[i];
            if (b != 0xFFu) {
                int pos = atomicAdd(&cur[b], 1);
                sbuf[pos] = pbuf[i];
                bsort[pos] = b;
            }
        }
        __syncthreads();
        // 5. write-out: consecutive i -> consecutive global slots per segment
        const int nv = scn[NSBMAX - 1];
        for (int i = t; i < nv; i += 256) {
            int b = bsort[i];
            int slot = gofs[b] + (i - base[b]);
            unsigned int p = sbuf[i];
            if (slot < SBCAP) {
                dst[(size_t)b * SBCAP + slot] = p;
            } else {
                int oi = atomicAdd(ovf_cnt, 1);
                if (oi < OVF_CAP)
                    ovf[oi] = ((unsigned long long)b << 32) | p;
            }
        }
        __syncthreads();   // protect buffers before next chunk
    }
}

// ---------------------------------------------------------------------------
// Phase 2: one block per 256-node output chunk. Coalesced read of its
// super-bucket region (4x redundant), filter to own sub-range, LDS-sort,
// fully-coalesced contiguous CSR write. No scattered global writes.
// ---------------------------------------------------------------------------
__global__ __launch_bounds__(256) void phase2_kernel(
        const unsigned int* __restrict__ dst,
        const int* __restrict__ gtot,
        const unsigned long long* __restrict__ ovf,
        const int* __restrict__ ovf_cnt,
        int* __restrict__ starts,
        int* __restrict__ cnt,
        int* __restrict__ src, int N) {
    __shared__ int hist[256], scn2[256], cur[256];
    __shared__ int sbuf[BCAP3];              // 64 KB
    const int b = blockIdx.x;                // 256-node chunk
    const int t = threadIdx.x;
    const int c0 = b * 256;
    const int sb = c0 >> SBSH;               // owning super-bucket
    const int sub = (c0 >> 8) & ((SB >> 8) - 1);   // sub-range 0..3
    const int m = min(gtot[sb], SBCAP);
    const unsigned int* reg = dst + (size_t)sb * SBCAP;

    hist[t] = 0;
    __syncthreads();
    // pass 1: histogram of own sub-range
    for (int i = t; i < m; i += 256) {
        unsigned int p = reg[i];
        int nl10 = p >> 17;
        if ((nl10 >> 8) == sub) atomicAdd(&hist[nl10 & 255], 1);
    }
    const int no = min(*ovf_cnt, OVF_CAP);
    for (int i = t; i < no; i += 256) {
        if ((int)(ovf[i] >> 32) == sb) {
            unsigned int p = (unsigned int)ovf[i];
            int nl10 = p >> 17;
            if ((nl10 >> 8) == sub) atomicAdd(&hist[nl10 & 255], 1);
        }
    }
    __syncthreads();
    int h = hist[t];
    scn2[t] = h;
    __syncthreads();
    for (int o = 1; o < 256; o <<= 1) {
        int v = (t >= o) ? scn2[t - o] : 0;
        __syncthreads();
        scn2[t] += v;
        __syncthreads();
    }
    int excl = scn2[t] - h;
    cur[t] = excl;
    const int bs = b * BCAP3;
    if (c0 + t < N) {
        starts[c0 + t] = bs + excl;
        cnt[c0 + t] = h;
    }
    __syncthreads();
    // pass 2: scatter r into LDS sorted-by-node order (region is L2-hot)
    for (int i = t; i < m; i += 256) {
        unsigned int p = reg[i];
        int nl10 = p >> 17;
        if ((nl10 >> 8) == sub) {
            int pos = atomicAdd(&cur[nl10 & 255], 1);
            if (pos < BCAP3) sbuf[pos] = (int)(p & 0x1FFFFu);
        }
    }
    for (int i = t; i < no; i += 256) {
        if ((int)(ovf[i] >> 32) == sb) {
            unsigned int p = (unsigned int)ovf[i];
            int nl10 = p >> 17;
            if ((nl10 >> 8) == sub) {
                int pos = atomicAdd(&cur[nl10 & 255], 1);
                if (pos < BCAP3) sbuf[pos] = (int)(p & 0x1FFFFu);
            }
        }
    }
    __syncthreads();
    // contiguous coalesced CSR write
    const int lim = min(scn2[255], BCAP3);
    for (int i = t; i < lim; i += 256) src[bs + i] = sbuf[i];
}

// ===========================================================================
// LEGACY DIRECT PATH (fallback only)
// ===========================================================================
__global__ void detect_kernel(const unsigned int* __restrict__ w,
                              unsigned int* __restrict__ flag) {
    unsigned int v = 0;
    for (int i = 1 + 2 * (int)threadIdx.x; i < 65536; i += 2 * (int)blockDim.x)
        v |= w[i];
    if (v) atomicOr(flag, 1u);
}

__global__ void fused_bucket_kernel(const void* __restrict__ adj,
                                    const unsigned int* __restrict__ flag,
                                    int* __restrict__ cnt,
                                    int* __restrict__ src2, int E, int N) {
    int e = blockIdx.x * blockDim.x + threadIdx.x;
    if (e >= E) return;
    int r, c;
    load_edge(adj, *flag, e, E, r, c);
    if (r == c) return;
    if ((unsigned)r >= (unsigned)N || (unsigned)c >= (unsigned)N) return;
    int pos = atomicAdd(&cnt[c], 1);
    if (pos < DM) src2[(size_t)c * DM + pos] = r;
}

// ---------------------------------------------------------------------------
// Gather: one wave per node. lane = (edge-group g 0..5, class-quad cl 0..9).
// dm > 0: direct mode; dm == 0: CSR mode. (verified, 45 us)
// ---------------------------------------------------------------------------
__global__ void gather_kernel(const unsigned short* __restrict__ xwb,
                              const int* __restrict__ starts,
                              const int* __restrict__ deg,
                              const int* __restrict__ src,
                              const float* __restrict__ bias,
                              float* __restrict__ out, int N, int dm) {
    int wid = (blockIdx.x * blockDim.x + threadIdx.x) >> 6;
    int lane = threadIdx.x & 63;
    if (wid >= N) return;
    int start, d;
    if (dm > 0) {
        start = wid * dm;
        d = min(deg[wid], dm);
    } else {
        start = starts[wid];
        d = deg[wid];
    }
    start = __builtin_amdgcn_readfirstlane(start);
    d     = __builtin_amdgcn_readfirstlane(d);

    const int g  = lane / 10;        // 0..5 edge groups; lanes 60-63 idle
    const int cl = lane % 10;        // class quad
    const bool lact = (g < 6);
    float a0 = 0.f, a1 = 0.f, a2 = 0.f, a3 = 0.f;

    if (g == 0) {                    // self-loop row
        ushort4 v = *reinterpret_cast<const ushort4*>(
            xwb + (size_t)wid * NCLS + cl * 4);
        a0 = bf2f(v.x); a1 = bf2f(v.y); a2 = bf2f(v.z); a3 = bf2f(v.w);
    }

    const int* sp = src + start;
    for (int e = 0; e < d; e += 12) {
        int i0 = e + g, i1 = e + 6 + g;
        if (lact && i0 < d) {
            int r = sp[i0];
            ushort4 v = *reinterpret_cast<const ushort4*>(
                xwb + (size_t)r * NCLS + cl * 4);
            a0 += bf2f(v.x); a1 += bf2f(v.y); a2 += bf2f(v.z); a3 += bf2f(v.w);
        }
        if (lact && i1 < d) {
            int r = sp[i1];
            ushort4 v = *reinterpret_cast<const ushort4*>(
                xwb + (size_t)r * NCLS + cl * 4);
            a0 += bf2f(v.x); a1 += bf2f(v.y); a2 += bf2f(v.z); a3 += bf2f(v.w);
        }
    }

    a0 += __shfl_down(a0, 30); a1 += __shfl_down(a1, 30);
    a2 += __shfl_down(a2, 30); a3 += __shfl_down(a3, 30);
    {
        float u0 = __shfl_down(a0, 10), v0 = __shfl_down(a0, 20);
        float u1 = __shfl_down(a1, 10), v1 = __shfl_down(a1, 20);
        float u2 = __shfl_down(a2, 10), v2 = __shfl_down(a2, 20);
        float u3 = __shfl_down(a3, 10), v3 = __shfl_down(a3, 20);
        a0 += u0 + v0; a1 += u1 + v1; a2 += u2 + v2; a3 += u3 + v3;
    }

    if (lane < 10) {
        float scale = 1.0f / (float)(d + 1);
        float4 bb = *reinterpret_cast<const float4*>(bias + cl * 4);
        float4 o;
        o.x = fmaf(scale, a0, bb.x);
        o.y = fmaf(scale, a1, bb.y);
        o.z = fmaf(scale, a2, bb.z);
        o.w = fmaf(scale, a3, bb.w);
        *reinterpret_cast<float4*>(out + (size_t)wid * NCLS + cl * 4) = o;
    }
}

extern "C" void kernel_launch(void* const* d_in, const int* in_sizes, int n_in,
                              void* d_out, int out_size, void* d_ws, size_t ws_size,
                              hipStream_t stream) {
    const float* x   = (const float*)d_in[0];
    const void*  adj = d_in[1];
    const float* W   = (const float*)d_in[2];
    const float* b   = (const float*)d_in[3];
    float* out = (float*)d_out;

    const int N = in_sizes[0] / NFEAT;   // 100000
    const int E = in_sizes[1] / 2;       // 3200000
    const int NSB = (N + SB - 1) / SB;   // 98 super-buckets
    const int NB = (N + 255) / 256;      // 391 output chunks
    const int GEMMB = (N + 63) / 64;

    char* ws = (char*)d_ws;
    size_t off = 0;
    auto alloc = [&](size_t bytes) { char* p = ws + off; off += (bytes + 15) & ~size_t(15); return p; };

    unsigned short* xwb = (unsigned short*)alloc((size_t)N * NCLS * 2);   // 8 MB
    int*   cnt          = (int*)  alloc((size_t)N * sizeof(int));
    unsigned int* flag  = (unsigned int*)alloc(16);
    int*   ovf_cnt      = (int*)  alloc(16);
    int*   gtot         = (int*)  alloc(NSBMAX * sizeof(int));
    unsigned short* Wb  = (unsigned short*)alloc((size_t)NPAD * NFEAT * 2);

    const size_t part_need = off
        + (((size_t)NSB * SBCAP * 4 + 15) & ~size_t(15))            // dst 14.5 MB
        + (((size_t)N * 4 + 15) & ~size_t(15))                      // starts
        + (((size_t)NB * BCAP3 * 4 + 15) & ~size_t(15))             // src 25.6 MB
        + (size_t)OVF_CAP * 8;                                      // ovf ring
    const bool partition = (NSB <= NSBMAX) && (E >= 512) && (part_need <= ws_size);
    const size_t direct_need = off + (size_t)N * DM * sizeof(int);
    const bool direct = !partition && (direct_need <= ws_size);

    wconv_kernel<<<(NPAD * NFEAT + 255) / 256, 256, 0, stream>>>(W, Wb, flag, ovf_cnt, gtot);

    if (partition) {
        unsigned int* dst = (unsigned int*)alloc((size_t)NSB * SBCAP * 4);
        int* starts = (int*)alloc((size_t)N * 4);
        int* src    = (int*)alloc((size_t)NB * BCAP3 * 4);
        unsigned long long* ovf = (unsigned long long*)alloc((size_t)OVF_CAP * 8);

        phase1_kernel<<<P1B, 256, 0, stream>>>(adj, dst, gtot, ovf, ovf_cnt, E, N);
        gemm_kernel<<<GEMMB, 256, 0, stream>>>(x, Wb, xwb, N);
        phase2_kernel<<<NB, 256, 0, stream>>>(dst, gtot, ovf, ovf_cnt,
                                              starts, cnt, src, N);
        gather_kernel<<<(N * 64 + 255) / 256, 256, 0, stream>>>(
            xwb, starts, cnt, src, b, out, N, 0);
    } else if (direct) {
        int* src2 = (int*)alloc((size_t)N * DM * sizeof(int));
        hipMemsetAsync(cnt, 0, (size_t)N * sizeof(int), stream);
        detect_kernel<<<1, 512, 0, stream>>>((const unsigned int*)adj, flag);
        gemm_kernel<<<GEMMB, 256, 0, stream>>>(x, Wb, xwb, N);
        fused_bucket_kernel<<<(E + 255) / 256, 256, 0, stream>>>(adj, flag, cnt, src2, E, N);
        gather_kernel<<<(N * 64 + 255) / 256, 256, 0, stream>>>(
            xwb, nullptr, cnt, src2, b, out, N, DM);
    }
}

// Round 15
// 243.564 us; speedup vs baseline: 4.1196x; 1.2563x over previous
//
#include <hip/hip_runtime.h>

#define NFEAT 512
#define NCLS  40
#define NPAD  48          // NCLS padded to 3 MFMA n-tiles of 16
#define DM 128            // padded bucket width (legacy direct path)

// 3-pass radix partition parameters
#define CSH     14        // coarse digit shift: c>>14 -> 8 regions of 16384 nodes
#define NCOARSE 8
#define REGCAP  614400    // per coarse region capacity (mean ~524K, >100 sigma)
#define CH      4096      // edges per LDS sort chunk
#define PAB     512       // pass A block count
#define PBB     512       // pass B block count
#define TASKS_PER_REG ((REGCAP + CH - 1) / CH)
#define NFBALL  512       // fine-bucket id space (c>>8), 391 used
#define BCAP3   12288     // CSR region per 256-node fine bucket (mean 8192)
#define OVF_CAP 65536     // overflow ring (never populated in practice)

typedef __attribute__((ext_vector_type(8))) short bf16x8;   // 8 bf16 (4 VGPRs)
typedef __attribute__((ext_vector_type(4))) float f32x4;

__device__ __forceinline__ unsigned short f2bf(float f) {   // RNE f32->bf16
    unsigned int u = __builtin_bit_cast(unsigned int, f);
    return (unsigned short)((u + 0x7FFFu + ((u >> 16) & 1u)) >> 16);
}
__device__ __forceinline__ float bf2f(unsigned short h) {
    return __builtin_bit_cast(float, (unsigned int)h << 16);
}

__device__ __forceinline__ void load_edge(const void* adj, int int32_mode,
                                          int e, int E, int& r, int& c) {
    if (int32_mode) {
        const int* a = (const int*)adj;
        r = a[e]; c = a[(size_t)E + e];
    } else {
        const long long* a = (const long long*)adj;
        r = (int)a[e]; c = (int)a[(size_t)E + e];
    }
}

// ---------------------------------------------------------------------------
// W conv + zero all control/reservation counters (one dispatch).
// ---------------------------------------------------------------------------
__global__ void wconv_kernel(const float* __restrict__ W,
                             unsigned short* __restrict__ Wb,
                             unsigned int* __restrict__ flag,
                             int* __restrict__ ovf_cnt,
                             int* __restrict__ gtotA,
                             int* __restrict__ gtotB) {
    int i = blockIdx.x * blockDim.x + threadIdx.x;
    if (i == 0) { *flag = 0u; *ovf_cnt = 0; }
    if (i < NCOARSE) gtotA[i] = 0;
    if (i < NFBALL)  gtotB[i] = 0;
    if (i >= NPAD * NFEAT) return;
    int n = i >> 9;
    float v = (n < NCLS) ? W[i] : 0.0f;
    Wb[i] = f2bf(v);
}

// ---------------------------------------------------------------------------
// GEMM: f32 x loads, in-register bf16 convert, MFMA, bf16 output. (verified)
// ---------------------------------------------------------------------------
__global__ __launch_bounds__(256) void gemm_kernel(
        const float* __restrict__ x, const unsigned short* __restrict__ Wb,
        unsigned short* __restrict__ xwb, int N) {
    const int wid  = (blockIdx.x * blockDim.x + threadIdx.x) >> 6;
    const int lane = threadIdx.x & 63;
    const int m0 = wid * 16;
    if (m0 >= N) return;
    const int frow = lane & 15, ks = lane >> 4;
    int grow = m0 + frow; if (grow > N - 1) grow = N - 1;
    const float* xr = x + (size_t)grow * NFEAT + ks * 8;
    const unsigned short* wb0 = Wb + (size_t)frow * NFEAT + ks * 8;
    const unsigned short* wb1 = wb0 + (size_t)16 * NFEAT;
    const unsigned short* wb2 = wb0 + (size_t)32 * NFEAT;

    f32x4 acc0 = {0.f, 0.f, 0.f, 0.f};
    f32x4 acc1 = {0.f, 0.f, 0.f, 0.f};
    f32x4 acc2 = {0.f, 0.f, 0.f, 0.f};

#pragma unroll
    for (int kk = 0; kk < NFEAT; kk += 32) {
        float4 xa = *reinterpret_cast<const float4*>(xr + kk);
        float4 xb = *reinterpret_cast<const float4*>(xr + kk + 4);
        bf16x8 a;
        a[0] = (short)f2bf(xa.x); a[1] = (short)f2bf(xa.y);
        a[2] = (short)f2bf(xa.z); a[3] = (short)f2bf(xa.w);
        a[4] = (short)f2bf(xb.x); a[5] = (short)f2bf(xb.y);
        a[6] = (short)f2bf(xb.z); a[7] = (short)f2bf(xb.w);
        bf16x8 b0 = *reinterpret_cast<const bf16x8*>(wb0 + kk);
        bf16x8 b1 = *reinterpret_cast<const bf16x8*>(wb1 + kk);
        bf16x8 b2 = *reinterpret_cast<const bf16x8*>(wb2 + kk);
        acc0 = __builtin_amdgcn_mfma_f32_16x16x32_bf16(a, b0, acc0, 0, 0, 0);
        acc1 = __builtin_amdgcn_mfma_f32_16x16x32_bf16(a, b1, acc1, 0, 0, 0);
        acc2 = __builtin_amdgcn_mfma_f32_16x16x32_bf16(a, b2, acc2, 0, 0, 0);
    }

    const int ccol = frow;
#pragma unroll
    for (int i = 0; i < 4; ++i) {
        int crow = m0 + ks * 4 + i;
        if (crow < N) {
            unsigned short* orow = xwb + (size_t)crow * NCLS;
            orow[ccol]      = f2bf(acc0[i]);
            orow[16 + ccol] = f2bf(acc1[i]);
            if (ccol < 8) orow[32 + ccol] = f2bf(acc2[i]);
        }
    }
}

// ---------------------------------------------------------------------------
// Pass A: chunk-sort by 3-bit coarse digit (8 regions). Segments avg 512
// entries (2 KB) -> near-perfect write coalescing. p = (c&16383)<<17 | r.
// ---------------------------------------------------------------------------
__global__ __launch_bounds__(256) void passA_kernel(
        const void* __restrict__ adj,
        unsigned int* __restrict__ dstA,      // [NCOARSE][REGCAP]
        int* __restrict__ gtotA,              // [NCOARSE]
        unsigned long long* __restrict__ ovf,
        int* __restrict__ ovf_cnt,
        int E, int N) {
    __shared__ unsigned int  pbuf[CH];        // 16 KB
    __shared__ unsigned char bbuf[CH];        // 4 KB
    __shared__ unsigned int  sbuf[CH];        // 16 KB
    __shared__ unsigned char bsort[CH];       // 4 KB
    __shared__ int hist[NCOARSE], base[NCOARSE + 1], cur[NCOARSE], gofs[NCOARSE];
    __shared__ unsigned int det;

    const int t = threadIdx.x;
    if (t == 0) det = 0u;
    __syncthreads();
    // inline dtype detect: odd 32-bit words all-zero <=> int64 storage
    const unsigned int* aw = (const unsigned int*)adj;
    unsigned int dv = aw[2 * t + 1] | aw[2 * (t + 256) + 1];
    if (dv) atomicOr(&det, 1u);
    __syncthreads();
    const int m32 = (det != 0);

    const int nchunks = (E + CH - 1) / CH;
    for (int ci = blockIdx.x; ci < nchunks; ci += gridDim.x) {
        const int cb = ci * CH;
        const int n = min(CH, E - cb);
        for (int i = t; i < CH; i += 256) {
            unsigned char b = 0xFFu; unsigned int p = 0;
            if (i < n) {
                int r, c;
                load_edge(adj, m32, cb + i, E, r, c);
                if (r != c && (unsigned)r < (unsigned)N && (unsigned)c < (unsigned)N) {
                    b = (unsigned char)(c >> CSH);
                    p = ((unsigned int)(c & ((1 << CSH) - 1)) << 17) | (unsigned int)r;
                }
            }
            bbuf[i] = b; pbuf[i] = p;
        }
        if (t < NCOARSE) hist[t] = 0;
        __syncthreads();
        for (int i = t; i < CH; i += 256) {
            unsigned char b = bbuf[i];
            if (b != 0xFFu) atomicAdd(&hist[b], 1);
        }
        __syncthreads();
        if (t == 0) {
            base[0] = 0;
            for (int k = 0; k < NCOARSE; ++k) base[k + 1] = base[k] + hist[k];
        }
        __syncthreads();
        if (t < NCOARSE) {
            cur[t] = base[t];
            gofs[t] = hist[t] ? atomicAdd(&gtotA[t], hist[t]) : 0;
        }
        __syncthreads();
        for (int i = t; i < CH; i += 256) {
            unsigned char b = bbuf[i];
            if (b != 0xFFu) {
                int pos = atomicAdd(&cur[b], 1);
                sbuf[pos] = pbuf[i];
                bsort[pos] = b;
            }
        }
        __syncthreads();
        const int nv = base[NCOARSE];
        for (int i = t; i < nv; i += 256) {
            int b = bsort[i];
            unsigned int p = sbuf[i];
            int slot = gofs[b] + (i - base[b]);
            if (slot < REGCAP) {
                dstA[(size_t)b * REGCAP + slot] = p;
            } else {                              // ~never (>100 sigma)
                int cfull = (b << CSH) | (int)(p >> 17);
                unsigned int q = ((unsigned int)(cfull & 255) << 17) | (p & 0x1FFFFu);
                int oi = atomicAdd(ovf_cnt, 1);
                if (oi < OVF_CAP)
                    ovf[oi] = ((unsigned long long)(cfull >> 8) << 32) | q;
            }
        }
        __syncthreads();
    }
}

// ---------------------------------------------------------------------------
// Pass B: per coarse region, re-sort chunks by 6-bit fine digit (64 buckets
// of 256 nodes). Segments avg 64 entries (256 B) -> coalesced. Output
// q = (c&255)<<17 | r into compact per-fine-bucket regions.
// ---------------------------------------------------------------------------
__global__ __launch_bounds__(256) void passB_kernel(
        const unsigned int* __restrict__ dstA,
        const int* __restrict__ gtotA,
        unsigned int* __restrict__ dstB,      // [NFBALL][BCAP3]
        int* __restrict__ gtotB,              // [NFBALL]
        unsigned long long* __restrict__ ovf,
        int* __restrict__ ovf_cnt) {
    __shared__ unsigned int  pbuf[CH];
    __shared__ unsigned char fbuf[CH];
    __shared__ unsigned int  sbuf[CH];
    __shared__ unsigned char fsort[CH];
    __shared__ int hist[64], base[65], cur[64], gofs[64];

    const int t = threadIdx.x;
    const int ntasks = NCOARSE * TASKS_PER_REG;
    for (int task = blockIdx.x; task < ntasks; task += gridDim.x) {
        const int g  = task / TASKS_PER_REG;
        const int ci = task - g * TASKS_PER_REG;
        const int len = min(gtotA[g], REGCAP);
        const int cb = ci * CH;
        if (cb >= len) continue;
        const int n = min(CH, len - cb);
        const unsigned int* regp = dstA + (size_t)g * REGCAP + cb;

        for (int i = t; i < CH; i += 256) {
            unsigned char f = 0xFFu; unsigned int p = 0;
            if (i < n) { p = regp[i]; f = (unsigned char)(p >> 25); }  // bits 8..13 of c
            fbuf[i] = f; pbuf[i] = p;
        }
        if (t < 64) hist[t] = 0;
        __syncthreads();
        for (int i = t; i < CH; i += 256) {
            unsigned char f = fbuf[i];
            if (f != 0xFFu) atomicAdd(&hist[f], 1);
        }
        __syncthreads();
        if (t == 0) {
            base[0] = 0;
            for (int k = 0; k < 64; ++k) base[k + 1] = base[k] + hist[k];
        }
        __syncthreads();
        if (t < 64) {
            cur[t] = base[t];
            int gfb = (g << 6) | t;
            gofs[t] = hist[t] ? atomicAdd(&gtotB[gfb], hist[t]) : 0;
        }
        __syncthreads();
        for (int i = t; i < CH; i += 256) {
            unsigned char f = fbuf[i];
            if (f != 0xFFu) {
                int pos = atomicAdd(&cur[f], 1);
                sbuf[pos] = pbuf[i];
                fsort[pos] = f;
            }
        }
        __syncthreads();
        const int nv = base[64];
        for (int i = t; i < nv; i += 256) {
            int f = fsort[i];
            unsigned int p = sbuf[i];
            unsigned int q = (((p >> 17) & 255u) << 17) | (p & 0x1FFFFu);
            int slot = gofs[f] + (i - base[f]);
            int gfb = (g << 6) | f;
            if (slot < BCAP3) {
                dstB[(size_t)gfb * BCAP3 + slot] = q;
            } else {
                int oi = atomicAdd(ovf_cnt, 1);
                if (oi < OVF_CAP)
                    ovf[oi] = ((unsigned long long)gfb << 32) | q;
            }
        }
        __syncthreads();
    }
}

// ---------------------------------------------------------------------------
// Phase 2: one block per fine bucket (391). Contiguous read of its compact
// region, 256-histogram -> scan -> LDS scatter -> coalesced CSR write.
// ---------------------------------------------------------------------------
__global__ __launch_bounds__(256) void phase2_kernel(
        const unsigned int* __restrict__ dstB,
        const int* __restrict__ gtotB,
        const unsigned long long* __restrict__ ovf,
        const int* __restrict__ ovf_cnt,
        int* __restrict__ starts,
        int* __restrict__ cnt,
        int* __restrict__ src, int N) {
    __shared__ int hist[256], scn2[256], cur[256];
    __shared__ int sbuf[BCAP3];               // 48 KB
    const int b = blockIdx.x, t = threadIdx.x;
    const int len = min(gtotB[b], BCAP3);
    const unsigned int* reg = dstB + (size_t)b * BCAP3;

    hist[t] = 0;
    __syncthreads();
    for (int i = t; i < len; i += 256)
        atomicAdd(&hist[reg[i] >> 17], 1);
    const int no = min(*ovf_cnt, OVF_CAP);
    for (int i = t; i < no; i += 256)
        if ((int)(ovf[i] >> 32) == b)
            atomicAdd(&hist[((unsigned int)ovf[i]) >> 17], 1);
    __syncthreads();
    int h = hist[t];
    scn2[t] = h;
    __syncthreads();
    for (int o = 1; o < 256; o <<= 1) {
        int v = (t >= o) ? scn2[t - o] : 0;
        __syncthreads();
        scn2[t] += v;
        __syncthreads();
    }
    int excl = scn2[t] - h;
    cur[t] = excl;
    const int bs = b * BCAP3;
    const int c0 = b * 256;
    if (c0 + t < N) { starts[c0 + t] = bs + excl; cnt[c0 + t] = h; }
    __syncthreads();
    for (int i = t; i < len; i += 256) {
        unsigned int q = reg[i];
        int pos = atomicAdd(&cur[q >> 17], 1);
        if (pos < BCAP3) sbuf[pos] = (int)(q & 0x1FFFFu);
    }
    for (int i = t; i < no; i += 256) {
        if ((int)(ovf[i] >> 32) == b) {
            unsigned int q = (unsigned int)ovf[i];
            int pos = atomicAdd(&cur[q >> 17], 1);
            if (pos < BCAP3) sbuf[pos] = (int)(q & 0x1FFFFu);
        }
    }
    __syncthreads();
    const int lim = min(scn2[255], BCAP3);
    for (int i = t; i < lim; i += 256) src[bs + i] = sbuf[i];
}

// ===========================================================================
// LEGACY DIRECT PATH (fallback only)
// ===========================================================================
__global__ void detect_kernel(const unsigned int* __restrict__ w,
                              unsigned int* __restrict__ flag) {
    unsigned int v = 0;
    for (int i = 1 + 2 * (int)threadIdx.x; i < 65536; i += 2 * (int)blockDim.x)
        v |= w[i];
    if (v) atomicOr(flag, 1u);
}

__global__ void fused_bucket_kernel(const void* __restrict__ adj,
                                    const unsigned int* __restrict__ flag,
                                    int* __restrict__ cnt,
                                    int* __restrict__ src2, int E, int N) {
    int e = blockIdx.x * blockDim.x + threadIdx.x;
    if (e >= E) return;
    int r, c;
    load_edge(adj, *flag, e, E, r, c);
    if (r == c) return;
    if ((unsigned)r >= (unsigned)N || (unsigned)c >= (unsigned)N) return;
    int pos = atomicAdd(&cnt[c], 1);
    if (pos < DM) src2[(size_t)c * DM + pos] = r;
}

// ---------------------------------------------------------------------------
// Gather: one wave per node. lane = (edge-group g 0..5, class-quad cl 0..9).
// dm > 0: direct mode; dm == 0: CSR mode. (verified, ~45 us)
// ---------------------------------------------------------------------------
__global__ void gather_kernel(const unsigned short* __restrict__ xwb,
                              const int* __restrict__ starts,
                              const int* __restrict__ deg,
                              const int* __restrict__ src,
                              const float* __restrict__ bias,
                              float* __restrict__ out, int N, int dm) {
    int wid = (blockIdx.x * blockDim.x + threadIdx.x) >> 6;
    int lane = threadIdx.x & 63;
    if (wid >= N) return;
    int start, d;
    if (dm > 0) {
        start = wid * dm;
        d = min(deg[wid], dm);
    } else {
        start = starts[wid];
        d = deg[wid];
    }
    start = __builtin_amdgcn_readfirstlane(start);
    d     = __builtin_amdgcn_readfirstlane(d);

    const int g  = lane / 10;        // 0..5 edge groups; lanes 60-63 idle
    const int cl = lane % 10;        // class quad
    const bool lact = (g < 6);
    float a0 = 0.f, a1 = 0.f, a2 = 0.f, a3 = 0.f;

    if (g == 0) {                    // self-loop row
        ushort4 v = *reinterpret_cast<const ushort4*>(
            xwb + (size_t)wid * NCLS + cl * 4);
        a0 = bf2f(v.x); a1 = bf2f(v.y); a2 = bf2f(v.z); a3 = bf2f(v.w);
    }

    const int* sp = src + start;
    for (int e = 0; e < d; e += 12) {
        int i0 = e + g, i1 = e + 6 + g;
        if (lact && i0 < d) {
            int r = sp[i0];
            ushort4 v = *reinterpret_cast<const ushort4*>(
                xwb + (size_t)r * NCLS + cl * 4);
            a0 += bf2f(v.x); a1 += bf2f(v.y); a2 += bf2f(v.z); a3 += bf2f(v.w);
        }
        if (lact && i1 < d) {
            int r = sp[i1];
            ushort4 v = *reinterpret_cast<const ushort4*>(
                xwb + (size_t)r * NCLS + cl * 4);
            a0 += bf2f(v.x); a1 += bf2f(v.y); a2 += bf2f(v.z); a3 += bf2f(v.w);
        }
    }

    a0 += __shfl_down(a0, 30); a1 += __shfl_down(a1, 30);
    a2 += __shfl_down(a2, 30); a3 += __shfl_down(a3, 30);
    {
        float u0 = __shfl_down(a0, 10), v0 = __shfl_down(a0, 20);
        float u1 = __shfl_down(a1, 10), v1 = __shfl_down(a1, 20);
        float u2 = __shfl_down(a2, 10), v2 = __shfl_down(a2, 20);
        float u3 = __shfl_down(a3, 10), v3 = __shfl_down(a3, 20);
        a0 += u0 + v0; a1 += u1 + v1; a2 += u2 + v2; a3 += u3 + v3;
    }

    if (lane < 10) {
        float scale = 1.0f / (float)(d + 1);
        float4 bb = *reinterpret_cast<const float4*>(bias + cl * 4);
        float4 o;
        o.x = fmaf(scale, a0, bb.x);
        o.y = fmaf(scale, a1, bb.y);
        o.z = fmaf(scale, a2, bb.z);
        o.w = fmaf(scale, a3, bb.w);
        *reinterpret_cast<float4*>(out + (size_t)wid * NCLS + cl * 4) = o;
    }
}

extern "C" void kernel_launch(void* const* d_in, const int* in_sizes, int n_in,
                              void* d_out, int out_size, void* d_ws, size_t ws_size,
                              hipStream_t stream) {
    const float* x   = (const float*)d_in[0];
    const void*  adj = d_in[1];
    const float* W   = (const float*)d_in[2];
    const float* b   = (const float*)d_in[3];
    float* out = (float*)d_out;

    const int N = in_sizes[0] / NFEAT;   // 100000
    const int E = in_sizes[1] / 2;       // 3200000
    const int NB = (N + 255) / 256;      // 391 fine buckets
    const int GEMMB = (N + 63) / 64;

    char* ws = (char*)d_ws;
    size_t off = 0;
    auto alloc = [&](size_t bytes) { char* p = ws + off; off += (bytes + 15) & ~size_t(15); return p; };

    unsigned short* xwb = (unsigned short*)alloc((size_t)N * NCLS * 2);   // 8 MB
    int*   cnt          = (int*)  alloc((size_t)N * sizeof(int));
    unsigned int* flag  = (unsigned int*)alloc(16);
    int*   ovf_cnt      = (int*)  alloc(16);
    int*   gtotA        = (int*)  alloc(NCOARSE * sizeof(int));
    int*   gtotB        = (int*)  alloc(NFBALL * sizeof(int));
    unsigned short* Wb  = (unsigned short*)alloc((size_t)NPAD * NFEAT * 2);

    const size_t part_need = off
        + (((size_t)NCOARSE * REGCAP * 4 + 15) & ~size_t(15))       // dstA 19.7 MB
        + (((size_t)NFBALL * BCAP3 * 4 + 15) & ~size_t(15))         // dstB 25.2 MB
        + (((size_t)N * 4 + 15) & ~size_t(15))                      // starts
        + (((size_t)NB * BCAP3 * 4 + 15) & ~size_t(15))             // src 19.2 MB
        + (size_t)OVF_CAP * 8;                                      // ovf ring
    const bool partition = (N <= (NCOARSE << CSH)) && (E >= 512)
                           && (part_need <= ws_size);
    const size_t direct_need = off + (size_t)N * DM * sizeof(int);
    const bool direct = !partition && (direct_need <= ws_size);

    wconv_kernel<<<(NPAD * NFEAT + 255) / 256, 256, 0, stream>>>(
        W, Wb, flag, ovf_cnt, gtotA, gtotB);

    if (partition) {
        unsigned int* dstA = (unsigned int*)alloc((size_t)NCOARSE * REGCAP * 4);
        unsigned int* dstB = (unsigned int*)alloc((size_t)NFBALL * BCAP3 * 4);
        int* starts = (int*)alloc((size_t)N * 4);
        int* src    = (int*)alloc((size_t)NB * BCAP3 * 4);
        unsigned long long* ovf = (unsigned long long*)alloc((size_t)OVF_CAP * 8);

        passA_kernel<<<PAB, 256, 0, stream>>>(adj, dstA, gtotA, ovf, ovf_cnt, E, N);
        passB_kernel<<<PBB, 256, 0, stream>>>(dstA, gtotA, dstB, gtotB, ovf, ovf_cnt);
        gemm_kernel<<<GEMMB, 256, 0, stream>>>(x, Wb, xwb, N);
        phase2_kernel<<<NB, 256, 0, stream>>>(dstB, gtotB, ovf, ovf_cnt,
                                              starts, cnt, src, N);
        gather_kernel<<<(N * 64 + 255) / 256, 256, 0, stream>>>(
            xwb, starts, cnt, src, b, out, N, 0);
    } else if (direct) {
        int* src2 = (int*)alloc((size_t)N * DM * sizeof(int));
        hipMemsetAsync(cnt, 0, (size_t)N * sizeof(int), stream);
        detect_kernel<<<1, 512, 0, stream>>>((const unsigned int*)adj, flag);
        gemm_kernel<<<GEMMB, 256, 0, stream>>>(x, Wb, xwb, N);
        fused_bucket_kernel<<<(E + 255) / 256, 256, 0, stream>>>(adj, flag, cnt, src2, E, N);
        gather_kernel<<<(N * 64 + 255) / 256, 256, 0, stream>>>(
            xwb, nullptr, cnt, src2, b, out, N, DM);
    }
}

// Round 16
// 233.684 us; speedup vs baseline: 4.2937x; 1.0423x over previous
//
#include <hip/hip_runtime.h>

#define NFEAT 512
#define NCLS  40
#define NPAD  48          // NCLS padded to 3 MFMA n-tiles of 16
#define DM 128            // padded bucket width (legacy direct path)

// partition parameters (R11 chunk-sort phase1 + slice format)
#define NFB     512       // fine-bucket id space (256 nodes each); 391 used
#define P1B     512       // phase-1 block count
#define CH      2048      // edges per LDS sort chunk
#define SCAP    64        // slice capacity per (bucket, block); mean ~12
#define BCAP3   12288     // CSR region per 256-node bucket (mean 8192)
#define OVF_CAP 65536     // overflow ring (never populated in practice)

typedef __attribute__((ext_vector_type(8))) short bf16x8;   // 8 bf16 (4 VGPRs)
typedef __attribute__((ext_vector_type(4))) float f32x4;

__device__ __forceinline__ unsigned short f2bf(float f) {   // RNE f32->bf16
    unsigned int u = __builtin_bit_cast(unsigned int, f);
    return (unsigned short)((u + 0x7FFFu + ((u >> 16) & 1u)) >> 16);
}
__device__ __forceinline__ float bf2f(unsigned short h) {
    return __builtin_bit_cast(float, (unsigned int)h << 16);
}

__device__ __forceinline__ void load_edge(const void* adj, int int32_mode,
                                          int e, int E, int& r, int& c) {
    if (int32_mode) {
        const int* a = (const int*)adj;
        r = a[e]; c = a[(size_t)E + e];
    } else {
        const long long* a = (const long long*)adj;
        r = (int)a[e]; c = (int)a[(size_t)E + e];
    }
}

// ---------------------------------------------------------------------------
// W [40][512] f32 -> Wb [48][512] bf16 (rows 40..47 zero); zero control vars.
// ---------------------------------------------------------------------------
__global__ void wconv_kernel(const float* __restrict__ W,
                             unsigned short* __restrict__ Wb,
                             unsigned int* __restrict__ flag,
                             int* __restrict__ ovf_cnt) {
    int i = blockIdx.x * blockDim.x + threadIdx.x;
    if (i == 0) { *flag = 0u; *ovf_cnt = 0; }
    if (i >= NPAD * NFEAT) return;
    int n = i >> 9;
    float v = (n < NCLS) ? W[i] : 0.0f;
    Wb[i] = f2bf(v);
}

// ===========================================================================
// FUSED: blocks [0, P1B) = R11 chunk-sort phase1; blocks [P1B, ...) = MFMA
// gemm. Independent stages co-scheduled so gemm hides under phase1.
// ===========================================================================
__global__ __launch_bounds__(256) void fused_p1_gemm(
        const float* __restrict__ x, const unsigned short* __restrict__ Wb,
        unsigned short* __restrict__ xwb, const void* __restrict__ adj,
        unsigned int* __restrict__ slices, int* __restrict__ slice_cnt,
        unsigned long long* __restrict__ ovf, int* __restrict__ ovf_cnt,
        int N, int E) {
    // phase-1 LDS (gemm role ignores; ~37 KB -> 4 blocks/CU)
    __shared__ unsigned int   pbuf[CH];
    __shared__ unsigned short bbuf[CH];
    __shared__ unsigned int   sbuf[CH];
    __shared__ unsigned int   obuf[CH];
    __shared__ int hist[NFB], base[NFB], cur[NFB], gcur[NFB];
    __shared__ int scn[256];
    __shared__ unsigned int det;

    const int t = threadIdx.x;

    if (blockIdx.x < P1B) {
        // ----- phase 1: LDS chunk-sort into per-(bucket,block) slices -----
        const int blk = blockIdx.x;
        for (int i = t; i < NFB; i += 256) gcur[i] = 0;
        if (t == 0) det = 0u;
        __syncthreads();
        // inline dtype detect: odd 32-bit words all-zero <=> int64 storage
        const unsigned int* aw = (const unsigned int*)adj;
        unsigned int dv = aw[2 * t + 1] | aw[2 * (t + 256) + 1];
        if (dv) atomicOr(&det, 1u);
        __syncthreads();
        const int m32 = (det != 0);

        const int per_blk = (E + P1B - 1) / P1B;
        const int e0 = blk * per_blk;
        const int e1 = min(E, e0 + per_blk);

        for (int cb = e0; cb < e1; cb += CH) {
            const int n = min(CH, e1 - cb);
            for (int i = t; i < CH; i += 256) {
                unsigned short b = 0xFFFFu; unsigned int p = 0;
                if (i < n) {
                    int r, c;
                    load_edge(adj, m32, cb + i, E, r, c);
                    if (r != c && (unsigned)r < (unsigned)N && (unsigned)c < (unsigned)N) {
                        b = (unsigned short)(c >> 8);
                        p = ((unsigned int)(c & 255) << 17) | (unsigned int)r;
                    }
                }
                bbuf[i] = b; pbuf[i] = p;
            }
            for (int i = t; i < NFB; i += 256) hist[i] = 0;
            __syncthreads();
            for (int i = t; i < CH; i += 256) {
                unsigned short b = bbuf[i];
                if (b != 0xFFFFu) atomicAdd(&hist[b], 1);
            }
            __syncthreads();
            int h0 = hist[2 * t], h1 = hist[2 * t + 1];
            int s = h0 + h1;
            scn[t] = s;
            __syncthreads();
            for (int o = 1; o < 256; o <<= 1) {
                int v = (t >= o) ? scn[t - o] : 0;
                __syncthreads();
                scn[t] += v;
                __syncthreads();
            }
            int excl = scn[t] - s;
            base[2 * t] = excl;           cur[2 * t] = excl;
            base[2 * t + 1] = excl + h0;  cur[2 * t + 1] = excl + h0;
            __syncthreads();
            for (int i = t; i < CH; i += 256) {
                unsigned short b = bbuf[i];
                if (b != 0xFFFFu) {
                    unsigned int p = pbuf[i];
                    int pos = atomicAdd(&cur[b], 1);
                    int rank = gcur[b] + (pos - base[b]);
                    unsigned int tgt;
                    if (rank < SCAP) {
                        tgt = ((unsigned int)b * P1B + (unsigned int)blk) * SCAP + rank;
                    } else {
                        tgt = 0xFFFFFFFFu;
                        int oi = atomicAdd(ovf_cnt, 1);
                        if (oi < OVF_CAP)
                            ovf[oi] = ((unsigned long long)b << 32) | p;
                    }
                    sbuf[pos] = p;
                    obuf[pos] = tgt;
                }
            }
            __syncthreads();
            const int nv = cur[NFB - 1];
            for (int i = t; i < nv; i += 256) {
                unsigned int tgt = obuf[i];
                if (tgt != 0xFFFFFFFFu) slices[tgt] = sbuf[i];
            }
            gcur[2 * t]     += h0;
            gcur[2 * t + 1] += h1;
            __syncthreads();
        }

        for (int i = t; i < NFB; i += 256)
            slice_cnt[(size_t)i * P1B + blk] = min(gcur[i], SCAP);
        return;
    }

    // ----- gemm role: xw = x @ W^T via mfma (verified R11/R14 code) -----
    const int wid  = (int)(blockIdx.x - P1B) * 4 + (t >> 6);
    const int lane = t & 63;
    const int m0 = wid * 16;
    if (m0 >= N) return;
    const int frow = lane & 15, ks = lane >> 4;
    int grow = m0 + frow; if (grow > N - 1) grow = N - 1;
    const float* xr = x + (size_t)grow * NFEAT + ks * 8;
    const unsigned short* wb0 = Wb + (size_t)frow * NFEAT + ks * 8;
    const unsigned short* wb1 = wb0 + (size_t)16 * NFEAT;
    const unsigned short* wb2 = wb0 + (size_t)32 * NFEAT;

    f32x4 acc0 = {0.f, 0.f, 0.f, 0.f};
    f32x4 acc1 = {0.f, 0.f, 0.f, 0.f};
    f32x4 acc2 = {0.f, 0.f, 0.f, 0.f};

#pragma unroll
    for (int kk = 0; kk < NFEAT; kk += 32) {
        float4 xa = *reinterpret_cast<const float4*>(xr + kk);
        float4 xb = *reinterpret_cast<const float4*>(xr + kk + 4);
        bf16x8 a;
        a[0] = (short)f2bf(xa.x); a[1] = (short)f2bf(xa.y);
        a[2] = (short)f2bf(xa.z); a[3] = (short)f2bf(xa.w);
        a[4] = (short)f2bf(xb.x); a[5] = (short)f2bf(xb.y);
        a[6] = (short)f2bf(xb.z); a[7] = (short)f2bf(xb.w);
        bf16x8 b0 = *reinterpret_cast<const bf16x8*>(wb0 + kk);
        bf16x8 b1 = *reinterpret_cast<const bf16x8*>(wb1 + kk);
        bf16x8 b2 = *reinterpret_cast<const bf16x8*>(wb2 + kk);
        acc0 = __builtin_amdgcn_mfma_f32_16x16x32_bf16(a, b0, acc0, 0, 0, 0);
        acc1 = __builtin_amdgcn_mfma_f32_16x16x32_bf16(a, b1, acc1, 0, 0, 0);
        acc2 = __builtin_amdgcn_mfma_f32_16x16x32_bf16(a, b2, acc2, 0, 0, 0);
    }

    const int ccol = frow;
#pragma unroll
    for (int i = 0; i < 4; ++i) {
        int crow = m0 + ks * 4 + i;
        if (crow < N) {
            unsigned short* orow = xwb + (size_t)crow * NCLS;
            orow[ccol]      = f2bf(acc0[i]);
            orow[16 + ccol] = f2bf(acc1[i]);
            if (ccol < 8) orow[32 + ccol] = f2bf(acc2[i]);
        }
    }
}

// ---------------------------------------------------------------------------
// Phase 2 (512 threads): one block per fine bucket. Coalesced predicated
// slice reads (thread<->slot), LDS hist -> scan -> LDS sbuf sort ->
// fully-coalesced CSR write. No scattered global writes.
// ---------------------------------------------------------------------------
__global__ __launch_bounds__(512) void phase2_kernel(
        const unsigned int* __restrict__ slices,
        const int* __restrict__ slice_cnt,
        const unsigned long long* __restrict__ ovf,
        const int* __restrict__ ovf_cnt,
        int* __restrict__ starts,
        int* __restrict__ cnt,
        int* __restrict__ src, int N) {
    __shared__ int hist[256], scn2[256], cur[256];
    __shared__ int scnt[P1B];                 // 2 KB
    __shared__ int sbuf[BCAP3];               // 48 KB
    const int b = blockIdx.x, t = threadIdx.x;
    const size_t sbase = (size_t)b * P1B * SCAP;

    if (t < 256) hist[t] = 0;
    scnt[t] = slice_cnt[(size_t)b * P1B + t];     // blockDim == P1B == 512
    __syncthreads();

    // pass 1: histogram (coalesced: consecutive threads -> consecutive slots)
    for (int i = t; i < P1B * SCAP; i += 512) {
        int s = i >> 6, k = i & 63;               // SCAP == 64
        if (k < scnt[s]) atomicAdd(&hist[slices[sbase + i] >> 17], 1);
    }
    const int no = min(*ovf_cnt, OVF_CAP);
    for (int i = t; i < no; i += 512)
        if ((int)(ovf[i] >> 32) == b)
            atomicAdd(&hist[((unsigned int)ovf[i]) >> 17], 1);
    __syncthreads();

    // exclusive scan over 256 (threads t<256)
    int h = 0;
    if (t < 256) { h = hist[t]; scn2[t] = h; }
    __syncthreads();
    for (int o = 1; o < 256; o <<= 1) {
        int v = 0;
        if (t < 256 && t >= o) v = scn2[t - o];
        __syncthreads();
        if (t < 256) scn2[t] += v;
        __syncthreads();
    }
    const int bs = b * BCAP3;
    if (t < 256) {
        int excl = scn2[t] - h;
        cur[t] = excl;
        int c = b * 256 + t;
        if (c < N) { starts[c] = bs + excl; cnt[c] = h; }
    }
    __syncthreads();

    // pass 2: scatter r into LDS sorted-by-node order
    for (int i = t; i < P1B * SCAP; i += 512) {
        int s = i >> 6, k = i & 63;
        if (k < scnt[s]) {
            unsigned int p = slices[sbase + i];
            int pos = atomicAdd(&cur[p >> 17], 1);
            if (pos < BCAP3) sbuf[pos] = (int)(p & 0x1FFFFu);
        }
    }
    for (int i = t; i < no; i += 512) {
        if ((int)(ovf[i] >> 32) == b) {
            unsigned int p = (unsigned int)ovf[i];
            int pos = atomicAdd(&cur[p >> 17], 1);
            if (pos < BCAP3) sbuf[pos] = (int)(p & 0x1FFFFu);
        }
    }
    __syncthreads();

    // fully-coalesced CSR write
    const int lim = min(scn2[255], BCAP3);
    for (int i = t; i < lim; i += 512) src[bs + i] = sbuf[i];
}

// ===========================================================================
// LEGACY DIRECT PATH (fallback only)
// ===========================================================================
__global__ void detect_kernel(const unsigned int* __restrict__ w,
                              unsigned int* __restrict__ flag) {
    unsigned int v = 0;
    for (int i = 1 + 2 * (int)threadIdx.x; i < 65536; i += 2 * (int)blockDim.x)
        v |= w[i];
    if (v) atomicOr(flag, 1u);
}

__global__ __launch_bounds__(256) void gemm_kernel(
        const float* __restrict__ x, const unsigned short* __restrict__ Wb,
        unsigned short* __restrict__ xwb, int N) {
    const int wid  = (blockIdx.x * blockDim.x + threadIdx.x) >> 6;
    const int lane = threadIdx.x & 63;
    const int m0 = wid * 16;
    if (m0 >= N) return;
    const int frow = lane & 15, ks = lane >> 4;
    int grow = m0 + frow; if (grow > N - 1) grow = N - 1;
    const float* xr = x + (size_t)grow * NFEAT + ks * 8;
    const unsigned short* wb0 = Wb + (size_t)frow * NFEAT + ks * 8;
    const unsigned short* wb1 = wb0 + (size_t)16 * NFEAT;
    const unsigned short* wb2 = wb0 + (size_t)32 * NFEAT;

    f32x4 acc0 = {0.f, 0.f, 0.f, 0.f};
    f32x4 acc1 = {0.f, 0.f, 0.f, 0.f};
    f32x4 acc2 = {0.f, 0.f, 0.f, 0.f};

#pragma unroll
    for (int kk = 0; kk < NFEAT; kk += 32) {
        float4 xa = *reinterpret_cast<const float4*>(xr + kk);
        float4 xb = *reinterpret_cast<const float4*>(xr + kk + 4);
        bf16x8 a;
        a[0] = (short)f2bf(xa.x); a[1] = (short)f2bf(xa.y);
        a[2] = (short)f2bf(xa.z); a[3] = (short)f2bf(xa.w);
        a[4] = (short)f2bf(xb.x); a[5] = (short)f2bf(xb.y);
        a[6] = (short)f2bf(xb.z); a[7] = (short)f2bf(xb.w);
        bf16x8 b0 = *reinterpret_cast<const bf16x8*>(wb0 + kk);
        bf16x8 b1 = *reinterpret_cast<const bf16x8*>(wb1 + kk);
        bf16x8 b2 = *reinterpret_cast<const bf16x8*>(wb2 + kk);
        acc0 = __builtin_amdgcn_mfma_f32_16x16x32_bf16(a, b0, acc0, 0, 0, 0);
        acc1 = __builtin_amdgcn_mfma_f32_16x16x32_bf16(a, b1, acc1, 0, 0, 0);
        acc2 = __builtin_amdgcn_mfma_f32_16x16x32_bf16(a, b2, acc2, 0, 0, 0);
    }

    const int ccol = frow;
#pragma unroll
    for (int i = 0; i < 4; ++i) {
        int crow = m0 + ks * 4 + i;
        if (crow < N) {
            unsigned short* orow = xwb + (size_t)crow * NCLS;
            orow[ccol]      = f2bf(acc0[i]);
            orow[16 + ccol] = f2bf(acc1[i]);
            if (ccol < 8) orow[32 + ccol] = f2bf(acc2[i]);
        }
    }
}

__global__ void fused_bucket_kernel(const void* __restrict__ adj,
                                    const unsigned int* __restrict__ flag,
                                    int* __restrict__ cnt,
                                    int* __restrict__ src2, int E, int N) {
    int e = blockIdx.x * blockDim.x + threadIdx.x;
    if (e >= E) return;
    int r, c;
    load_edge(adj, *flag, e, E, r, c);
    if (r == c) return;
    if ((unsigned)r >= (unsigned)N || (unsigned)c >= (unsigned)N) return;
    int pos = atomicAdd(&cnt[c], 1);
    if (pos < DM) src2[(size_t)c * DM + pos] = r;
}

// ---------------------------------------------------------------------------
// Gather: one wave per node. lane = (edge-group g 0..5, class-quad cl 0..9).
// dm > 0: direct mode; dm == 0: CSR mode. (verified)
// ---------------------------------------------------------------------------
__global__ void gather_kernel(const unsigned short* __restrict__ xwb,
                              const int* __restrict__ starts,
                              const int* __restrict__ deg,
                              const int* __restrict__ src,
                              const float* __restrict__ bias,
                              float* __restrict__ out, int N, int dm) {
    int wid = (blockIdx.x * blockDim.x + threadIdx.x) >> 6;
    int lane = threadIdx.x & 63;
    if (wid >= N) return;
    int start, d;
    if (dm > 0) {
        start = wid * dm;
        d = min(deg[wid], dm);
    } else {
        start = starts[wid];
        d = deg[wid];
    }
    start = __builtin_amdgcn_readfirstlane(start);
    d     = __builtin_amdgcn_readfirstlane(d);

    const int g  = lane / 10;        // 0..5 edge groups; lanes 60-63 idle
    const int cl = lane % 10;        // class quad
    const bool lact = (g < 6);
    float a0 = 0.f, a1 = 0.f, a2 = 0.f, a3 = 0.f;

    if (g == 0) {                    // self-loop row
        ushort4 v = *reinterpret_cast<const ushort4*>(
            xwb + (size_t)wid * NCLS + cl * 4);
        a0 = bf2f(v.x); a1 = bf2f(v.y); a2 = bf2f(v.z); a3 = bf2f(v.w);
    }

    const int* sp = src + start;
    for (int e = 0; e < d; e += 12) {
        int i0 = e + g, i1 = e + 6 + g;
        if (lact && i0 < d) {
            int r = sp[i0];
            ushort4 v = *reinterpret_cast<const ushort4*>(
                xwb + (size_t)r * NCLS + cl * 4);
            a0 += bf2f(v.x); a1 += bf2f(v.y); a2 += bf2f(v.z); a3 += bf2f(v.w);
        }
        if (lact && i1 < d) {
            int r = sp[i1];
            ushort4 v = *reinterpret_cast<const ushort4*>(
                xwb + (size_t)r * NCLS + cl * 4);
            a0 += bf2f(v.x); a1 += bf2f(v.y); a2 += bf2f(v.z); a3 += bf2f(v.w);
        }
    }

    a0 += __shfl_down(a0, 30); a1 += __shfl_down(a1, 30);
    a2 += __shfl_down(a2, 30); a3 += __shfl_down(a3, 30);
    {
        float u0 = __shfl_down(a0, 10), v0 = __shfl_down(a0, 20);
        float u1 = __shfl_down(a1, 10), v1 = __shfl_down(a1, 20);
        float u2 = __shfl_down(a2, 10), v2 = __shfl_down(a2, 20);
        float u3 = __shfl_down(a3, 10), v3 = __shfl_down(a3, 20);
        a0 += u0 + v0; a1 += u1 + v1; a2 += u2 + v2; a3 += u3 + v3;
    }

    if (lane < 10) {
        float scale = 1.0f / (float)(d + 1);
        float4 bb = *reinterpret_cast<const float4*>(bias + cl * 4);
        float4 o;
        o.x = fmaf(scale, a0, bb.x);
        o.y = fmaf(scale, a1, bb.y);
        o.z = fmaf(scale, a2, bb.z);
        o.w = fmaf(scale, a3, bb.w);
        *reinterpret_cast<float4*>(out + (size_t)wid * NCLS + cl * 4) = o;
    }
}

extern "C" void kernel_launch(void* const* d_in, const int* in_sizes, int n_in,
                              void* d_out, int out_size, void* d_ws, size_t ws_size,
                              hipStream_t stream) {
    const float* x   = (const float*)d_in[0];
    const void*  adj = d_in[1];
    const float* W   = (const float*)d_in[2];
    const float* b   = (const float*)d_in[3];
    float* out = (float*)d_out;

    const int N = in_sizes[0] / NFEAT;   // 100000
    const int E = in_sizes[1] / 2;       // 3200000
    const int NB = (N + 255) / 256;      // 391 fine buckets
    const int GEMMB = (N + 63) / 64;     // 4 waves x 16 rows per block

    char* ws = (char*)d_ws;
    size_t off = 0;
    auto alloc = [&](size_t bytes) { char* p = ws + off; off += (bytes + 15) & ~size_t(15); return p; };

    unsigned short* xwb = (unsigned short*)alloc((size_t)N * NCLS * 2);   // 8 MB
    int*   cnt          = (int*)  alloc((size_t)N * sizeof(int));
    unsigned int* flag  = (unsigned int*)alloc(16);
    int*   ovf_cnt      = (int*)  alloc(16);
    unsigned short* Wb  = (unsigned short*)alloc((size_t)NPAD * NFEAT * 2);

    const size_t part_need = off
        + (((size_t)NFB * P1B * SCAP * 4 + 15) & ~size_t(15))       // slices 67 MB
        + (((size_t)NFB * P1B * 4 + 15) & ~size_t(15))              // slice_cnt 1 MB
        + (((size_t)N * 4 + 15) & ~size_t(15))                      // starts
        + (((size_t)NB * BCAP3 * 4 + 15) & ~size_t(15))             // src 19.2 MB
        + (size_t)OVF_CAP * 8;                                      // ovf ring
    const bool partition = (N <= NFB * 256) && (E >= 512) && (part_need <= ws_size);
    const size_t direct_need = off + (size_t)N * DM * sizeof(int);
    const bool direct = !partition && (direct_need <= ws_size);

    wconv_kernel<<<(NPAD * NFEAT + 255) / 256, 256, 0, stream>>>(W, Wb, flag, ovf_cnt);

    if (partition) {
        unsigned int* slices = (unsigned int*)alloc((size_t)NFB * P1B * SCAP * 4);
        int* slice_cnt = (int*)alloc((size_t)NFB * P1B * 4);
        int* starts = (int*)alloc((size_t)N * 4);
        int* src    = (int*)alloc((size_t)NB * BCAP3 * 4);
        unsigned long long* ovf = (unsigned long long*)alloc((size_t)OVF_CAP * 8);

        fused_p1_gemm<<<P1B + GEMMB, 256, 0, stream>>>(
            x, Wb, xwb, adj, slices, slice_cnt, ovf, ovf_cnt, N, E);
        phase2_kernel<<<NB, 512, 0, stream>>>(slices, slice_cnt, ovf, ovf_cnt,
                                              starts, cnt, src, N);
        gather_kernel<<<(N * 64 + 255) / 256, 256, 0, stream>>>(
            xwb, starts, cnt, src, b, out, N, 0);
    } else if (direct) {
        int* src2 = (int*)alloc((size_t)N * DM * sizeof(int));
        hipMemsetAsync(cnt, 0, (size_t)N * sizeof(int), stream);
        detect_kernel<<<1, 512, 0, stream>>>((const unsigned int*)adj, flag);
        gemm_kernel<<<GEMMB, 256, 0, stream>>>(x, Wb, xwb, N);
        fused_bucket_kernel<<<(E + 255) / 256, 256, 0, stream>>>(adj, flag, cnt, src2, E, N);
        gather_kernel<<<(N * 64 + 255) / 256, 256, 0, stream>>>(
            xwb, nullptr, cnt, src2, b, out, N, DM);
    }
}